// Round 1
// baseline (25.877 us; speedup 1.0000x reference)
//
#include <hip/hip_runtime.h>

#define B_ 8
#define LQ_ 64
#define LK_ 256
#define E_ 128
#define H_ 4
#define D_ 32
#define NH_ 128
#define EK_ 32

// ---------------------------------------------------------------------------
// Round-5: split each q-pair block into two single-row blocks.
//   512 blocks x 512 threads -> 2 blocks/CU (16 waves/CU) so barrier drains
//   and cold-miss latency of one block hide under the other block's compute.
//   Per-thread serial work halves (~480 FMA vs ~960).
// Per block (b, q):
//   qp[c]   = query[b,q,:] @ Wq + bq              (bk cancels in softmax)
//   g[h][e] = (1/sqrt(EK)) * sum_j Wk[e,h*32+j] * qp[h*32+j]
//   s[h][k] = key[b,k,:] . g[h,:]
//   p ~ mask * exp(s - m);  x[h*32+d] = num/den;  out = x @ Wo + bo
// Phase 5 rebalanced: thread = (2 k-rows) x (4 h) x (32-e chunk):
//   g LDS broadcasts drop 128->32 f4/thread vs the old (k, e-half) mapping.
// XCD swizzle (bijective, 512%8==0): each XCD owns one batch -> key/value/
//   mask (~400 KB) stay resident in its private 4 MB L2.
// ---------------------------------------------------------------------------
__global__ __launch_bounds__(512, 4) void fused_attn_kernel(
    const float* __restrict__ query, const float* __restrict__ key,
    const float* __restrict__ value, const int* __restrict__ mask,
    const float* __restrict__ Wq, const float* __restrict__ bq,
    const float* __restrict__ Wk,
    const float* __restrict__ Wo, const float* __restrict__ bo,
    float* __restrict__ out)
{
    const int blk0 = blockIdx.x;                 // 512 blocks
    const int blk  = (blk0 & 7) * 64 + (blk0 >> 3);  // XCD-chunked (bijective)
    const int b = blk >> 6;                      // batch == XCD
    const int q = blk & 63;
    const int t = threadIdx.x;

    __shared__ float e_lds[4 * LK_];             // [h][k] exp values (4 KB)
    __shared__ float smem[5248];                 // 20.5 KB aliased scratch

    float* qpart = smem;                         // [4eq][128]       ph2-3
    float* qp    = smem + 512;                   // [128]            ph3-4
    float* g     = smem + 640;                   // [4h][128]        ph4-5
    float* spart = smem + 1152;                  // [4ec][4h][256k]  ph5-6
    float* nump  = smem;                         // [16kg][4h][32d]  ph8-9
    float* denp  = smem + 2048;                  // [16kg][4h][32d]  ph8-9
    float* x     = smem + 4352;                  // [128]            ph9-10
    float* opart = smem + 4480;                  // [4dq][128]       ph10-11

    // ---- 0. prefetch value/mask into regs (completes behind phases 2-6) ----
    const int d  = t & 31;
    const int kg = t >> 5;                       // 16 k-groups of 16
    float vv[16], mfv[16];
    {
        const float* vb = value + ((size_t)(b * LK_) + kg * 16) * D_ + d;
        const int*   mb = mask  + ((size_t)(b * LK_) + kg * 16) * D_ + d;
        #pragma unroll
        for (int j = 0; j < 16; ++j) {
            vv[j]  = vb[j * D_];
            mfv[j] = (float)mb[j * D_];
        }
    }

    // ---- 2. qp partials: query read directly (lane-uniform L1 broadcast) ---
    {
        const int col = t & 127;
        const int eq  = t >> 7;                  // 0..3 : 32-row slab of Wq
        const float4* qr4 = reinterpret_cast<const float4*>(
            query + ((size_t)(b * LQ_) + q) * E_ + eq * 32);
        const float* wq = Wq + (size_t)(eq * 32) * E_ + col;
        float acc = 0.0f;
        #pragma unroll
        for (int j = 0; j < 8; ++j) {
            float4 qv = qr4[j];
            acc = fmaf(qv.x, wq[(size_t)(j * 4 + 0) * E_], acc);
            acc = fmaf(qv.y, wq[(size_t)(j * 4 + 1) * E_], acc);
            acc = fmaf(qv.z, wq[(size_t)(j * 4 + 2) * E_], acc);
            acc = fmaf(qv.w, wq[(size_t)(j * 4 + 3) * E_], acc);
        }
        qpart[eq * 128 + col] = acc;
    }
    __syncthreads();

    // ---- 3. qp finalize (one wave, f4) ----
    if (t < 32) {
        float4 s0 = reinterpret_cast<const float4*>(qpart)[t];
        float4 s1 = reinterpret_cast<const float4*>(qpart)[32 + t];
        float4 s2 = reinterpret_cast<const float4*>(qpart)[64 + t];
        float4 s3 = reinterpret_cast<const float4*>(qpart)[96 + t];
        float4 bv = reinterpret_cast<const float4*>(bq)[t];
        float4 r;
        r.x = s0.x + s1.x + s2.x + s3.x + bv.x;
        r.y = s0.y + s1.y + s2.y + s3.y + bv.y;
        r.z = s0.z + s1.z + s2.z + s3.z + bv.z;
        r.w = s0.w + s1.w + s2.w + s3.w + bv.w;
        reinterpret_cast<float4*>(qp)[t] = r;
    }
    __syncthreads();

    // ---- 4. g[h][e] = (1/sqrt(EK)) * Wk[e, h*32:+32] . qp[h*32:+32] ----
    {
        const float inv_sqrt_ek = 0.17677669529663687f;  // 1/sqrt(32)
        const int e = t & 127;
        const int h = t >> 7;                    // 0..3
        const float4* wk4 =
            reinterpret_cast<const float4*>(Wk + (size_t)e * E_ + h * EK_);
        const float4* qp4 = reinterpret_cast<const float4*>(qp + h * EK_);
        float acc = 0.0f;
        #pragma unroll
        for (int j = 0; j < 8; ++j) {
            float4 w  = wk4[j];
            float4 pv = qp4[j];
            acc = fmaf(w.x, pv.x, acc);
            acc = fmaf(w.y, pv.y, acc);
            acc = fmaf(w.z, pv.z, acc);
            acc = fmaf(w.w, pv.w, acc);
        }
        g[h * 128 + e] = acc * inv_sqrt_ek;
    }
    __syncthreads();

    // ---- 5. score partials: thread = (2 k) x (4 h) x (32-e chunk) ----
    {
        const int kq = t & 127;                  // k-pair index
        const int ec = t >> 7;                   // 0..3 : 32-e chunk
        const float4* kr0 = reinterpret_cast<const float4*>(
            key + ((size_t)(b * LK_) + kq * 2 + 0) * E_ + ec * 32);
        const float4* kr1 = reinterpret_cast<const float4*>(
            key + ((size_t)(b * LK_) + kq * 2 + 1) * E_ + ec * 32);
        float acc0[4] = {0.f, 0.f, 0.f, 0.f};
        float acc1[4] = {0.f, 0.f, 0.f, 0.f};
        #pragma unroll
        for (int j = 0; j < 8; ++j) {
            float4 k0 = kr0[j];
            float4 k1 = kr1[j];
            #pragma unroll
            for (int h = 0; h < 4; ++h) {
                float4 gg =
                    reinterpret_cast<const float4*>(g + h * 128 + ec * 32)[j];
                acc0[h] = fmaf(k0.x, gg.x, acc0[h]);
                acc0[h] = fmaf(k0.y, gg.y, acc0[h]);
                acc0[h] = fmaf(k0.z, gg.z, acc0[h]);
                acc0[h] = fmaf(k0.w, gg.w, acc0[h]);
                acc1[h] = fmaf(k1.x, gg.x, acc1[h]);
                acc1[h] = fmaf(k1.y, gg.y, acc1[h]);
                acc1[h] = fmaf(k1.z, gg.z, acc1[h]);
                acc1[h] = fmaf(k1.w, gg.w, acc1[h]);
            }
        }
        #pragma unroll
        for (int h = 0; h < 4; ++h) {
            *reinterpret_cast<float2*>(&spart[(ec * 4 + h) * 256 + kq * 2]) =
                make_float2(acc0[h], acc1[h]);
        }
    }
    __syncthreads();

    // ---- 6+7. combine e-chunks + max + exp (wave w<4 owns h=w) ----
    {
        const int w = t >> 6;
        if (w < 4) {
            const int h = w;
            const int l = t & 63;                // k-quad
            float4 s = *reinterpret_cast<const float4*>(
                &spart[h * 256 + l * 4]);
            #pragma unroll
            for (int ec = 1; ec < 4; ++ec) {
                float4 s2 = *reinterpret_cast<const float4*>(
                    &spart[(ec * 4 + h) * 256 + l * 4]);
                s.x += s2.x; s.y += s2.y; s.z += s2.z; s.w += s2.w;
            }
            float m = fmaxf(fmaxf(s.x, s.y), fmaxf(s.z, s.w));
            #pragma unroll
            for (int off = 32; off; off >>= 1)
                m = fmaxf(m, __shfl_xor(m, off));
            float4 e4;
            e4.x = __expf(s.x - m); e4.y = __expf(s.y - m);
            e4.z = __expf(s.z - m); e4.w = __expf(s.w - m);
            *reinterpret_cast<float4*>(&e_lds[h * LK_ + l * 4]) = e4;
        }
    }
    __syncthreads();

    // ---- 8. masked num/den over k (v/mask already in regs) ----
    {
        float num[4] = {0.f, 0.f, 0.f, 0.f};
        float den[4] = {0.f, 0.f, 0.f, 0.f};
        #pragma unroll
        for (int jq = 0; jq < 4; ++jq) {
            const float4 mf4 = make_float4(mfv[jq*4+0], mfv[jq*4+1],
                                           mfv[jq*4+2], mfv[jq*4+3]);
            const float4 mv4 = make_float4(mfv[jq*4+0]*vv[jq*4+0],
                                           mfv[jq*4+1]*vv[jq*4+1],
                                           mfv[jq*4+2]*vv[jq*4+2],
                                           mfv[jq*4+3]*vv[jq*4+3]);
            #pragma unroll
            for (int h = 0; h < 4; ++h) {
                float4 ev = *reinterpret_cast<const float4*>(
                    &e_lds[h * LK_ + kg * 16 + jq * 4]);
                num[h] = fmaf(ev.x, mv4.x, num[h]);
                num[h] = fmaf(ev.y, mv4.y, num[h]);
                num[h] = fmaf(ev.z, mv4.z, num[h]);
                num[h] = fmaf(ev.w, mv4.w, num[h]);
                den[h] = fmaf(ev.x, mf4.x, den[h]);
                den[h] = fmaf(ev.y, mf4.y, den[h]);
                den[h] = fmaf(ev.z, mf4.z, den[h]);
                den[h] = fmaf(ev.w, mf4.w, den[h]);
            }
        }
        #pragma unroll
        for (int h = 0; h < 4; ++h) {
            nump[(kg * 4 + h) * 32 + d] = num[h];
            denp[(kg * 4 + h) * 32 + d] = den[h];
        }
    }
    __syncthreads();

    // ---- 9. x = num/den ----
    if (t < 128) {
        const int h = t >> 5, dd = t & 31;
        float n = 0.f, dn = 0.f;
        #pragma unroll
        for (int k2 = 0; k2 < 16; ++k2) {
            n  += nump[(k2 * 4 + h) * 32 + dd];
            dn += denp[(k2 * 4 + h) * 32 + dd];
        }
        x[h * 32 + dd] = n / dn;
    }
    __syncthreads();

    // ---- 10. out projection partials: thread = (col) x (32-dim quarter) ----
    {
        const int col = t & 127;
        const int dq  = t >> 7;                  // 0..3
        const float* wo = Wo + (size_t)(dq * 32) * NH_ + col;
        const float4* x4 = reinterpret_cast<const float4*>(x + dq * 32);
        float acc = 0.0f;
        #pragma unroll
        for (int j = 0; j < 8; ++j) {
            float4 xv = x4[j];
            acc = fmaf(xv.x, wo[(size_t)(j * 4 + 0) * NH_], acc);
            acc = fmaf(xv.y, wo[(size_t)(j * 4 + 1) * NH_], acc);
            acc = fmaf(xv.z, wo[(size_t)(j * 4 + 2) * NH_], acc);
            acc = fmaf(xv.w, wo[(size_t)(j * 4 + 3) * NH_], acc);
        }
        opart[dq * 128 + col] = acc;
    }
    __syncthreads();

    // ---- 11. finalize + store the row ----
    if (t < 128) {
        float s = bo[t];
        #pragma unroll
        for (int dq = 0; dq < 4; ++dq)
            s += opart[dq * 128 + t];
        out[((size_t)(b * LQ_) + q) * NH_ + t] = s;
    }
}

extern "C" void kernel_launch(void* const* d_in, const int* in_sizes, int n_in,
                              void* d_out, int out_size, void* d_ws, size_t ws_size,
                              hipStream_t stream) {
    const float* query = (const float*)d_in[0];
    const float* key   = (const float*)d_in[1];
    const float* value = (const float*)d_in[2];
    const int*   mask  = (const int*)d_in[3];
    const float* Wq    = (const float*)d_in[4];
    const float* bq    = (const float*)d_in[5];
    const float* Wk    = (const float*)d_in[6];
    // d_in[7] = bk: k-constant in scores -> cancels in softmax -> unused
    const float* Wo    = (const float*)d_in[8];
    const float* bo    = (const float*)d_in[9];
    float* out = (float*)d_out;

    fused_attn_kernel<<<B_ * LQ_, 512, 0, stream>>>(
        query, key, value, mask, Wq, bq, Wk, Wo, bo, out);
}

// Round 2
// 18.491 us; speedup vs baseline: 1.3994x; 1.3994x over previous
//
#include <hip/hip_runtime.h>

#define B_ 8
#define LQ_ 64
#define LK_ 256
#define E_ 128
#define H_ 4
#define D_ 32
#define NH_ 128
#define EK_ 32

// ---------------------------------------------------------------------------
// Round-6: back to the proven 256-block / 2-row structure (R4, 17.3us), but
// with 1024 threads per block (16 waves/CU instead of 8).
//   - Per-CU global traffic, L1 transactions, LDS ops, FMA: IDENTICAL to R4.
//   - Per-thread serial work halves in every phase; 2x waves hide the
//     latency of the strided key/Wk reads between barriers.
//   (R5's 512-block split doubled per-CU traffic and regressed 17.3->25.9;
//    this doubles overlap at constant traffic instead.)
// Extra: phase 8 combines kg-pairs in-wave via shfl_xor(32) before the LDS
// write -> nump/denp LDS traffic and phase-9 reads halve.
// Math (bk cancels in softmax):
//   qp[r] = query[b,q0+r,:] @ Wq + bq
//   g[rh=r*4+h][e] = (1/sqrt(EK)) * sum_j Wk[e, h*32+j] * qp[r, h*32+j]
//   s[rh][k] = key[b,k,:] . g[rh,:]
//   p ~ mask * exp(s - m);  x[r][h*32+d] = num/den;  out = x @ Wo + bo
// ---------------------------------------------------------------------------
__global__ __launch_bounds__(1024, 4) void fused_attn_kernel(
    const float* __restrict__ query, const float* __restrict__ key,
    const float* __restrict__ value, const int* __restrict__ mask,
    const float* __restrict__ Wq, const float* __restrict__ bq,
    const float* __restrict__ Wk,
    const float* __restrict__ Wo, const float* __restrict__ bo,
    float* __restrict__ out)
{
    const int blk = blockIdx.x;       // 256 blocks
    const int b  = blk >> 5;
    const int q0 = (blk & 31) * 2;
    const int t  = threadIdx.x;

    __shared__ float e_lds[8 * LK_];  // [rh][k] exp values (8 KB)
    __shared__ float smem[10752];     // 42 KB aliased scratch

    float* qrow  = smem;              // [2][128]          (ph 1-2)
    float* qpart = smem + 256;        // [8z][128]         (2-3)
    float* qp    = smem + 1280;       // [2][128]          (3-4)
    float* g     = smem + 1536;       // [8rh][128]        (4-5)
    float* spart = smem + 2560;       // [4zc][8rh][256k]  (5-6)
    float* nump  = smem;              // [16][8][32]       (8-9)
    float* denp  = smem + 4096;       // [16][8][32]       (8-9)
    float* x     = smem + 8192;       // [2][128]          (9-10)
    float* opart = smem + 8448;       // [8][128]          (10-11)

    // ---- 0. prefetch value/mask into regs (completes behind phases 1-6) ----
    const int d  = t & 31;
    const int kg = t >> 5;            // 32 k-groups of 8
    float vv[8], mfv[8];
    {
        const float* vb = value + ((size_t)(b * LK_) + kg * 8) * D_ + d;
        const int*   mb = mask  + ((size_t)(b * LK_) + kg * 8) * D_ + d;
        #pragma unroll
        for (int j = 0; j < 8; ++j) {
            vv[j]  = vb[j * D_];
            mfv[j] = (float)mb[j * D_];
        }
    }

    // ---- 1. two query rows -> LDS ----
    if (t < 64) {
        reinterpret_cast<float4*>(qrow)[t] =
            reinterpret_cast<const float4*>(query + ((size_t)(b * LQ_) + q0) * E_)[t];
    }
    __syncthreads();

    // ---- 2. qp partials: thread (col, z = c4*2 + r), 32-c chunk each ----
    {
        const int col = t & 127;
        const int z   = t >> 7;       // 0..7
        const int r   = z & 1;
        const int c4  = z >> 1;       // 0..3 : 32-row slab of Wq
        const float4* qr4 = reinterpret_cast<const float4*>(qrow + r * 128 + c4 * 32);
        const float* wq = Wq + (size_t)(c4 * 32) * E_ + col;
        float acc = 0.0f;
        #pragma unroll
        for (int j = 0; j < 8; ++j) {
            float4 qv = qr4[j];
            acc = fmaf(qv.x, wq[(size_t)(j * 4 + 0) * E_], acc);
            acc = fmaf(qv.y, wq[(size_t)(j * 4 + 1) * E_], acc);
            acc = fmaf(qv.z, wq[(size_t)(j * 4 + 2) * E_], acc);
            acc = fmaf(qv.w, wq[(size_t)(j * 4 + 3) * E_], acc);
        }
        qpart[z * 128 + col] = acc;   // z == c4*2 + r
    }
    __syncthreads();

    // ---- 3. qp finalize ----
    if (t < 256) {
        const int col = t & 127, r = t >> 7;
        float s = bq[col];
        #pragma unroll
        for (int c4 = 0; c4 < 4; ++c4)
            s += qpart[(c4 * 2 + r) * 128 + col];
        qp[r * 128 + col] = s;
    }
    __syncthreads();

    // ---- 4. g[rh][e]: thread (r = t&1, h = (t>>1)&3, e = t>>3) ----
    // r-adjacent lanes share the same Wk line (broadcast); 32 lines/instr.
    {
        const float inv_sqrt_ek = 0.17677669529663687f;  // 1/sqrt(32)
        const int r = t & 1;
        const int h = (t >> 1) & 3;
        const int e = t >> 3;         // 0..127
        const float4* wk4 = reinterpret_cast<const float4*>(Wk + (size_t)e * E_ + h * EK_);
        const float4* qp4 = reinterpret_cast<const float4*>(qp + r * 128 + h * EK_);
        float acc = 0.0f;
        #pragma unroll
        for (int j = 0; j < 8; ++j) {
            float4 w  = wk4[j];
            float4 pv = qp4[j];
            acc = fmaf(w.x, pv.x, acc);
            acc = fmaf(w.y, pv.y, acc);
            acc = fmaf(w.z, pv.z, acc);
            acc = fmaf(w.w, pv.w, acc);
        }
        g[(r * 4 + h) * 128 + e] = acc * inv_sqrt_ek;
    }
    __syncthreads();

    // ---- 5. score partials: thread (k = t&255, zc = t>>8 : 32-e chunk) ----
    // key lines get 1x16B per lane (as R4); g reads are lane-uniform b128
    // broadcasts. Per-CU instruction totals identical to R4, spread 2x waves.
    {
        const int k  = t & 255;
        const int zc = t >> 8;        // 0..3
        const float4* kr =
            reinterpret_cast<const float4*>(key + ((size_t)(b * LK_) + k) * E_ + zc * 32);
        float acc[8] = {0.f, 0.f, 0.f, 0.f, 0.f, 0.f, 0.f, 0.f};
        #pragma unroll
        for (int j = 0; j < 8; ++j) {
            float4 kv = kr[j];
            #pragma unroll
            for (int rh = 0; rh < 8; ++rh) {
                float4 gg = reinterpret_cast<const float4*>(g + rh * 128 + zc * 32)[j];
                acc[rh] = fmaf(kv.x, gg.x, acc[rh]);
                acc[rh] = fmaf(kv.y, gg.y, acc[rh]);
                acc[rh] = fmaf(kv.z, gg.z, acc[rh]);
                acc[rh] = fmaf(kv.w, gg.w, acc[rh]);
            }
        }
        #pragma unroll
        for (int rh = 0; rh < 8; ++rh)
            spart[(zc * 8 + rh) * 256 + k] = acc[rh];
    }
    __syncthreads();

    // ---- 6+7. combine e-chunks + max + exp (wave w<8 owns rh=w) ----
    {
        const int w = t >> 6;
        if (w < 8) {
            const int l = t & 63;     // k-quad
            float4 s = *reinterpret_cast<const float4*>(&spart[w * 256 + l * 4]);
            #pragma unroll
            for (int zc = 1; zc < 4; ++zc) {
                float4 s2 = *reinterpret_cast<const float4*>(
                    &spart[(zc * 8 + w) * 256 + l * 4]);
                s.x += s2.x; s.y += s2.y; s.z += s2.z; s.w += s2.w;
            }
            float m = fmaxf(fmaxf(s.x, s.y), fmaxf(s.z, s.w));
            #pragma unroll
            for (int off = 32; off; off >>= 1)
                m = fmaxf(m, __shfl_xor(m, off));
            float4 e4;
            e4.x = __expf(s.x - m); e4.y = __expf(s.y - m);
            e4.z = __expf(s.z - m); e4.w = __expf(s.w - m);
            *reinterpret_cast<float4*>(&e_lds[w * LK_ + l * 4]) = e4;
        }
    }
    __syncthreads();

    // ---- 8. masked num/den over 8 k each; in-wave kg-pair combine ----
    {
        float num[8] = {0.f, 0.f, 0.f, 0.f, 0.f, 0.f, 0.f, 0.f};
        float den[8] = {0.f, 0.f, 0.f, 0.f, 0.f, 0.f, 0.f, 0.f};
        #pragma unroll
        for (int jq = 0; jq < 2; ++jq) {
            const float4 mf4 = make_float4(mfv[jq*4+0], mfv[jq*4+1],
                                           mfv[jq*4+2], mfv[jq*4+3]);
            const float4 mv4 = make_float4(mfv[jq*4+0]*vv[jq*4+0],
                                           mfv[jq*4+1]*vv[jq*4+1],
                                           mfv[jq*4+2]*vv[jq*4+2],
                                           mfv[jq*4+3]*vv[jq*4+3]);
            #pragma unroll
            for (int rh = 0; rh < 8; ++rh) {
                float4 ev = *reinterpret_cast<const float4*>(
                    &e_lds[rh * LK_ + kg * 8 + jq * 4]);
                num[rh] = fmaf(ev.x, mv4.x, num[rh]);
                num[rh] = fmaf(ev.y, mv4.y, num[rh]);
                num[rh] = fmaf(ev.z, mv4.z, num[rh]);
                num[rh] = fmaf(ev.w, mv4.w, num[rh]);
                den[rh] = fmaf(ev.x, mf4.x, den[rh]);
                den[rh] = fmaf(ev.y, mf4.y, den[rh]);
                den[rh] = fmaf(ev.z, mf4.z, den[rh]);
                den[rh] = fmaf(ev.w, mf4.w, den[rh]);
            }
        }
        // lanes l and l^32 hold kg and kg^1 (same d): combine pairs in-wave
        #pragma unroll
        for (int rh = 0; rh < 8; ++rh) {
            num[rh] += __shfl_xor(num[rh], 32);
            den[rh] += __shfl_xor(den[rh], 32);
        }
        if ((kg & 1) == 0) {
            const int kgp = kg >> 1;  // 0..15
            #pragma unroll
            for (int rh = 0; rh < 8; ++rh) {
                nump[(kgp * 8 + rh) * 32 + d] = num[rh];
                denp[(kgp * 8 + rh) * 32 + d] = den[rh];
            }
        }
    }
    __syncthreads();

    // ---- 9. x = num/den ----
    if (t < 256) {
        const int rh = t >> 5, dd = t & 31;
        float n = 0.f, dn = 0.f;
        #pragma unroll
        for (int k2 = 0; k2 < 16; ++k2) {
            n  += nump[(k2 * 8 + rh) * 32 + dd];
            dn += denp[(k2 * 8 + rh) * 32 + dd];
        }
        x[(rh >> 2) * 128 + (rh & 3) * 32 + dd] = n / dn;
    }
    __syncthreads();

    // ---- 10. out projection: thread (col, z = dq*2 + r), 32-dim quarter ----
    {
        const int col = t & 127;
        const int z   = t >> 7;       // 0..7
        const int r   = z & 1;
        const int dq  = z >> 1;       // 0..3
        const float* wo = Wo + (size_t)(dq * 32) * NH_ + col;
        const float4* x4 = reinterpret_cast<const float4*>(x + r * 128 + dq * 32);
        float acc = 0.0f;
        #pragma unroll
        for (int j = 0; j < 8; ++j) {
            float4 xv = x4[j];
            acc = fmaf(xv.x, wo[(size_t)(j * 4 + 0) * NH_], acc);
            acc = fmaf(xv.y, wo[(size_t)(j * 4 + 1) * NH_], acc);
            acc = fmaf(xv.z, wo[(size_t)(j * 4 + 2) * NH_], acc);
            acc = fmaf(xv.w, wo[(size_t)(j * 4 + 3) * NH_], acc);
        }
        opart[(dq * 2 + r) * 128 + col] = acc;
    }
    __syncthreads();

    // ---- 11. finalize + store both rows ----
    if (t < 256) {
        const int col = t & 127, r = t >> 7;
        float s = bo[col];
        #pragma unroll
        for (int dq = 0; dq < 4; ++dq)
            s += opart[(dq * 2 + r) * 128 + col];
        out[((size_t)(b * LQ_) + q0 + r) * NH_ + col] = s;
    }
}

extern "C" void kernel_launch(void* const* d_in, const int* in_sizes, int n_in,
                              void* d_out, int out_size, void* d_ws, size_t ws_size,
                              hipStream_t stream) {
    const float* query = (const float*)d_in[0];
    const float* key   = (const float*)d_in[1];
    const float* value = (const float*)d_in[2];
    const int*   mask  = (const int*)d_in[3];
    const float* Wq    = (const float*)d_in[4];
    const float* bq    = (const float*)d_in[5];
    const float* Wk    = (const float*)d_in[6];
    // d_in[7] = bk: k-constant in scores -> cancels in softmax -> unused
    const float* Wo    = (const float*)d_in[8];
    const float* bo    = (const float*)d_in[9];
    float* out = (float*)d_out;

    fused_attn_kernel<<<B_ * (LQ_ / 2), 1024, 0, stream>>>(
        query, key, value, mask, Wq, bq, Wk, Wo, bo, out);
}

// Round 3
// 18.310 us; speedup vs baseline: 1.4132x; 1.0099x over previous
//
#include <hip/hip_runtime.h>

#define B_ 8
#define LQ_ 64
#define LK_ 256
#define E_ 128
#define H_ 4
#define D_ 32
#define NH_ 128
#define EK_ 32

// ---------------------------------------------------------------------------
// Round-7: R4 structure/mappings EXACTLY (proven 17.3us), plus load-latency
// consolidation:
//  - ph0 hoists: query row (t<64), bq/bo scalars, Wk fragment (8xf4/thread).
//    These drain at the ph1->2 __syncthreads (early, while L1 is idle).
//  - phase-3 start issues key rows (16xf4/thread) + value/mask prefetches.
//    vmcnt is IN-ORDER, so these are issued after phase-2's Wq loads and
//    before any later global load -> nothing waits on them until use.
//  - ph3->4 and ph4->5 barriers are raw "lgkmcnt(0); s_barrier" (no vmcnt
//    drain) so key/value/mask stay in flight across phases 3-4 and are
//    awaited by their first use (phase 5 kreg / phase 8 vv,mfv).
//  - phases 4 and 5 become pure VALU + LDS (operands in registers).
// Per-CU traffic identical to R4; the gathers now stream concurrently
// behind compute instead of serializing one per barrier interval.
// ---------------------------------------------------------------------------

#define RAW_BARRIER() asm volatile("s_waitcnt lgkmcnt(0)\n\ts_barrier" ::: "memory")

__global__ __launch_bounds__(512, 2) void fused_attn_kernel(
    const float* __restrict__ query, const float* __restrict__ key,
    const float* __restrict__ value, const int* __restrict__ mask,
    const float* __restrict__ Wq, const float* __restrict__ bq,
    const float* __restrict__ Wk,
    const float* __restrict__ Wo, const float* __restrict__ bo,
    float* __restrict__ out)
{
    const int blk = blockIdx.x;       // 256 blocks
    const int b  = blk >> 5;
    const int q0 = (blk & 31) * 2;
    const int t  = threadIdx.x;

    __shared__ float e_lds[8 * LK_];  // [rh][k] exp values (8 KB)
    __shared__ float smem[9472];      // 37 KB aliased scratch

    float* qrow  = smem;              // [2][128]          (phases 1-2)
    float* qpart = smem + 256;        // [4][128]          (2-3)
    float* qp    = smem + 768;        // [2][128]          (3-4)
    float* g     = smem + 1024;       // [8][128]          (4-5)
    float* spart = smem + 2048;       // [2eh][8rh][256k]  (5-6)
    float* nump  = smem;              // [16][8][32]       (8-9)
    float* denp  = smem + 4096;       // [16][8][32]       (8-9)
    float* x     = smem + 8192;       // [2][128]          (9-10)
    float* opart = smem + 8448;       // [4eq][2r][128]    (10-11)

    // ---- 0. hoisted loads (drain at ph1->2 barrier, early) ----
    float4 qv0;
    if (t < 64)
        qv0 = reinterpret_cast<const float4*>(query + ((size_t)(b * LQ_) + q0) * E_)[t];
    float bqv = 0.0f, bov = 0.0f;
    if (t < 256) {
        bqv = bq[t & 127];
        bov = bo[t & 127];
    }
    const int e4 = t >> 2, p4 = t & 3;   // phase-4 mapping
    float4 wkr[8];
    {
        const float4* wk4 =
            reinterpret_cast<const float4*>(Wk + (size_t)e4 * E_ + p4 * EK_);
        #pragma unroll
        for (int j = 0; j < 8; ++j) wkr[j] = wk4[j];
    }

    // ---- 1. two query rows -> LDS ----
    if (t < 64) {
        reinterpret_cast<float4*>(qrow)[t] = qv0;
    }
    __syncthreads();   // drains query/bq/bo/Wk loads (cheap, L1 otherwise idle)

    // ---- 2. qp partials: thread (col, z=(eh<<1)|r), f4 qrow broadcasts ----
    {
        const int col = t & 127;
        const int z   = t >> 7;
        const int r   = z & 1;
        const int eh  = z >> 1;
        const float4* qr4 = reinterpret_cast<const float4*>(qrow + r * 128 + eh * 64);
        const float* wq = Wq + (size_t)(eh * 64) * E_ + col;
        float acc = 0.0f;
        #pragma unroll
        for (int j = 0; j < 16; ++j) {
            float4 qv = qr4[j];
            acc = fmaf(qv.x, wq[(size_t)(j * 4 + 0) * E_], acc);
            acc = fmaf(qv.y, wq[(size_t)(j * 4 + 1) * E_], acc);
            acc = fmaf(qv.z, wq[(size_t)(j * 4 + 2) * E_], acc);
            acc = fmaf(qv.w, wq[(size_t)(j * 4 + 3) * E_], acc);
        }
        qpart[z * 128 + col] = acc;
    }
    __syncthreads();   // Wq loads already consumed in-phase; drain ~free

    // ---- issue key + value/mask prefetches (in flight through ph3-4) ----
    const int k5 = t & 255, eh5 = t >> 8;
    float4 kreg[16];
    {
        const float4* kr = reinterpret_cast<const float4*>(
            key + ((size_t)(b * LK_) + k5) * E_ + eh5 * 64);
        #pragma unroll
        for (int j = 0; j < 16; ++j) kreg[j] = kr[j];
    }
    const int d  = t & 31;
    const int kg = t >> 5;            // 16 k-groups of 16
    float vv[16], mfv[16];
    {
        const float* vb = value + ((size_t)(b * LK_) + kg * 16) * D_ + d;
        const int*   mb = mask  + ((size_t)(b * LK_) + kg * 16) * D_ + d;
        #pragma unroll
        for (int j = 0; j < 16; ++j) {
            vv[j]  = vb[j * D_];
            mfv[j] = (float)mb[j * D_];
        }
    }

    // ---- 3. qp finalize (bq from register) ----
    if (t < 256) {
        const int col = t & 127, r = t >> 7;
        qp[r * 128 + col] =
            qpart[r * 128 + col] + qpart[(2 + r) * 128 + col] + bqv;
    }
    RAW_BARRIER();     // no vmcnt drain: key/vm stay in flight

    // ---- 4. g[rh][e]: Wk fragment already in registers ----
    {
        const float inv_sqrt_ek = 0.17677669529663687f;  // 1/sqrt(32)
        #pragma unroll
        for (int r = 0; r < 2; ++r) {
            const float4* qp4 = reinterpret_cast<const float4*>(qp + r * 128 + p4 * EK_);
            float acc = 0.0f;
            #pragma unroll
            for (int j = 0; j < 8; ++j) {
                float4 pv = qp4[j];
                acc = fmaf(wkr[j].x, pv.x, acc);
                acc = fmaf(wkr[j].y, pv.y, acc);
                acc = fmaf(wkr[j].z, pv.z, acc);
                acc = fmaf(wkr[j].w, pv.w, acc);
            }
            g[(r * 4 + p4) * 128 + e4] = acc * inv_sqrt_ek;
        }
    }
    RAW_BARRIER();     // no vmcnt drain: key/vm still in flight

    // ---- 5. score partials from key registers + g LDS broadcasts ----
    {
        float acc[8] = {0.f, 0.f, 0.f, 0.f, 0.f, 0.f, 0.f, 0.f};
        #pragma unroll
        for (int j = 0; j < 16; ++j) {
            float4 kv = kreg[j];     // first use -> in-order vmcnt wait here
            #pragma unroll
            for (int rh = 0; rh < 8; ++rh) {
                float4 gg = reinterpret_cast<const float4*>(g + rh * 128 + eh5 * 64)[j];
                acc[rh] = fmaf(kv.x, gg.x, acc[rh]);
                acc[rh] = fmaf(kv.y, gg.y, acc[rh]);
                acc[rh] = fmaf(kv.z, gg.z, acc[rh]);
                acc[rh] = fmaf(kv.w, gg.w, acc[rh]);
            }
        }
        #pragma unroll
        for (int rh = 0; rh < 8; ++rh)
            spart[(eh5 * 8 + rh) * 256 + k5] = acc[rh];
    }
    __syncthreads();

    // ---- 6+7. combine e-halves + max + exp (fused; wave w owns rh=w) ----
    {
        const int w = t >> 6;        // rh
        const int l = t & 63;        // k-quad
        float4 s0 = *reinterpret_cast<const float4*>(&spart[w * 256 + l * 4]);
        float4 s1 = *reinterpret_cast<const float4*>(&spart[(8 + w) * 256 + l * 4]);
        s0.x += s1.x; s0.y += s1.y; s0.z += s1.z; s0.w += s1.w;
        float m = fmaxf(fmaxf(s0.x, s0.y), fmaxf(s0.z, s0.w));
        #pragma unroll
        for (int off = 32; off; off >>= 1)
            m = fmaxf(m, __shfl_xor(m, off));
        float4 e;
        e.x = __expf(s0.x - m); e.y = __expf(s0.y - m);
        e.z = __expf(s0.z - m); e.w = __expf(s0.w - m);
        *reinterpret_cast<float4*>(&e_lds[w * LK_ + l * 4]) = e;
    }
    __syncthreads();

    // ---- 8. masked num/den over k: f4 e_lds reads (2-way = free) ----
    {
        float num[8] = {0.f, 0.f, 0.f, 0.f, 0.f, 0.f, 0.f, 0.f};
        float den[8] = {0.f, 0.f, 0.f, 0.f, 0.f, 0.f, 0.f, 0.f};
        #pragma unroll
        for (int jq = 0; jq < 4; ++jq) {
            const float4 mv4 = make_float4(mfv[jq*4+0]*vv[jq*4+0], mfv[jq*4+1]*vv[jq*4+1],
                                           mfv[jq*4+2]*vv[jq*4+2], mfv[jq*4+3]*vv[jq*4+3]);
            const float4 mf4 = make_float4(mfv[jq*4+0], mfv[jq*4+1],
                                           mfv[jq*4+2], mfv[jq*4+3]);
            #pragma unroll
            for (int rh = 0; rh < 8; ++rh) {
                float4 ev = *reinterpret_cast<const float4*>(
                    &e_lds[rh * LK_ + kg * 16 + jq * 4]);
                num[rh] = fmaf(ev.x, mv4.x, num[rh]);
                num[rh] = fmaf(ev.y, mv4.y, num[rh]);
                num[rh] = fmaf(ev.z, mv4.z, num[rh]);
                num[rh] = fmaf(ev.w, mv4.w, num[rh]);
                den[rh] = fmaf(ev.x, mf4.x, den[rh]);
                den[rh] = fmaf(ev.y, mf4.y, den[rh]);
                den[rh] = fmaf(ev.z, mf4.z, den[rh]);
                den[rh] = fmaf(ev.w, mf4.w, den[rh]);
            }
        }
        #pragma unroll
        for (int rh = 0; rh < 8; ++rh) {
            nump[(kg * 8 + rh) * 32 + d] = num[rh];
            denp[(kg * 8 + rh) * 32 + d] = den[rh];
        }
    }
    __syncthreads();

    // ---- 9. x = num/den ----
    if (t < 256) {
        const int rh = t >> 5, dd = t & 31;
        float n = 0.f, dn = 0.f;
        #pragma unroll
        for (int k2 = 0; k2 < 16; ++k2) {
            n  += nump[(k2 * 8 + rh) * 32 + dd];
            dn += denp[(k2 * 8 + rh) * 32 + dd];
        }
        x[(rh >> 2) * 128 + (rh & 3) * 32 + dd] = n / dn;
    }
    __syncthreads();

    // ---- 10. out projection, f4 x broadcasts, Wo read once (r inside) ----
    {
        const int col = t & 127;
        const int eq  = t >> 7;      // 0..3
        const int c0  = eq * 32;
        const float* wo = Wo + (size_t)c0 * NH_ + col;
        const float4* x40 = reinterpret_cast<const float4*>(x + c0);
        const float4* x41 = reinterpret_cast<const float4*>(x + 128 + c0);
        float acc0 = 0.f, acc1 = 0.f;
        #pragma unroll
        for (int j = 0; j < 8; ++j) {
            float4 xv0 = x40[j];
            float4 xv1 = x41[j];
            float w0 = wo[(size_t)(j * 4 + 0) * NH_];
            float w1 = wo[(size_t)(j * 4 + 1) * NH_];
            float w2 = wo[(size_t)(j * 4 + 2) * NH_];
            float w3 = wo[(size_t)(j * 4 + 3) * NH_];
            acc0 = fmaf(xv0.x, w0, acc0); acc1 = fmaf(xv1.x, w0, acc1);
            acc0 = fmaf(xv0.y, w1, acc0); acc1 = fmaf(xv1.y, w1, acc1);
            acc0 = fmaf(xv0.z, w2, acc0); acc1 = fmaf(xv1.z, w2, acc1);
            acc0 = fmaf(xv0.w, w3, acc0); acc1 = fmaf(xv1.w, w3, acc1);
        }
        opart[(eq * 2 + 0) * 128 + col] = acc0;
        opart[(eq * 2 + 1) * 128 + col] = acc1;
    }
    __syncthreads();

    // ---- 11. finalize + store both rows (bo from register) ----
    if (t < 256) {
        const int col = t & 127, r = t >> 7;
        float s = bov;
        #pragma unroll
        for (int eq = 0; eq < 4; ++eq)
            s += opart[(eq * 2 + r) * 128 + col];
        out[((size_t)(b * LQ_) + q0 + r) * NH_ + col] = s;
    }
}

extern "C" void kernel_launch(void* const* d_in, const int* in_sizes, int n_in,
                              void* d_out, int out_size, void* d_ws, size_t ws_size,
                              hipStream_t stream) {
    const float* query = (const float*)d_in[0];
    const float* key   = (const float*)d_in[1];
    const float* value = (const float*)d_in[2];
    const int*   mask  = (const int*)d_in[3];
    const float* Wq    = (const float*)d_in[4];
    const float* bq    = (const float*)d_in[5];
    const float* Wk    = (const float*)d_in[6];
    // d_in[7] = bk: k-constant in scores -> cancels in softmax -> unused
    const float* Wo    = (const float*)d_in[8];
    const float* bo    = (const float*)d_in[9];
    float* out = (float*)d_out;

    fused_attn_kernel<<<B_ * (LQ_ / 2), 512, 0, stream>>>(
        query, key, value, mask, Wq, bq, Wk, Wo, bo, out);
}